// Round 1
// 405.478 us; speedup vs baseline: 1.0314x; 1.0314x over previous
//
#include <hip/hip_runtime.h>

#define NN 100000
#define NE 200000
#define MT (NN + NE)

typedef unsigned short u16;
typedef __attribute__((ext_vector_type(8))) short bf16x8;
typedef __attribute__((ext_vector_type(4))) float f32x4;

__device__ __forceinline__ float bf2f(u16 u) {
    union { unsigned int i; float f; } v; v.i = ((unsigned int)u) << 16; return v.f;
}
__device__ __forceinline__ u16 f2bf(float f) {
    union { unsigned int i; float f; } v; v.f = f;
    unsigned int r = v.i + 0x7fffu + ((v.i >> 16) & 1u);
    return (u16)(r >> 16);
}
__device__ __forceinline__ void unpack2(unsigned int u, float& lo, float& hi) {
    union { unsigned int i; float f; } a, b;
    a.i = u << 16; b.i = u & 0xffff0000u;
    lo = a.f; hi = b.f;
}
__device__ __forceinline__ unsigned int pack2(float a, float b) {
    return (unsigned int)f2bf(a) | ((unsigned int)f2bf(b) << 16);
}
// Dtype-flexible scalar load (R2-R4 proven): f32 flag ? float : bf16.
__device__ __forceinline__ float loadf(const void* p, size_t i, int f32) {
    return f32 ? ((const float*)p)[i] : bf2f(((const u16*)p)[i]);
}
__device__ __forceinline__ void acc8(float a[8], uint4 g) {
    float e0, e1, e2, e3, e4, e5, e6, e7;
    unpack2(g.x, e0, e1); unpack2(g.y, e2, e3);
    unpack2(g.z, e4, e5); unpack2(g.w, e6, e7);
    a[0] += e0; a[1] += e1; a[2] += e2; a[3] += e3;
    a[4] += e4; a[5] += e5; a[6] += e6; a[7] += e7;
}

// Detect input dtype from bit patterns of x (R2-R4 proven). flag=1 => fp32.
__global__ void detect_kernel(const unsigned int* __restrict__ x, int* flag) {
    __shared__ int cnt;
    if (threadIdx.x == 0) cnt = 0;
    __syncthreads();
    int bad = 0;
    for (int i = threadIdx.x; i < 1024; i += 256) {
        unsigned int e = (x[i] >> 7) & 0xFF;
        if (e == 0xFF || (e > 0 && (e < 107 || e > 134))) bad++;
    }
    atomicAdd(&cnt, bad);
    __syncthreads();
    if (threadIdx.x == 0) *flag = (cnt > 256) ? 1 : 0;
}

// Build MFMA B-operand fragments (bf16) and summed f32 biases.
// Bf[b*512 + lane*8 + j] = W_m[k][f], m=b>>1, k=(lane>>4)*8+j,
// f=(b&1)*16+(lane&15)  — the 16x16x32 B-operand layout.
// Raw-gather restructure: the linear maps now apply AFTER aggregation, so
// x side m: [theta_x | theta_deg | theta_r0 | theta_r1]           (8 frags)
// y side m: [gamma_y | gamma_deg | gamma_r0 | gamma_r1 | gamma_x | theta_y]
//                                                                 (12 frags)
__global__ __launch_bounds__(256) void prep_kernel(
    const void* txw, const void* tdw, const void* tyw,
    const void* gyw, const void* gdw, const void* gxw,
    const void* trw, const void* grw,
    const void* txb, const void* tdb, const void* tyb,
    const void* gyb, const void* gdb, const void* gxb,
    const void* trb, const void* grb,
    u16* Bfx, u16* Bfy, float* bx, float* by, const int* flagp)
{
    int f32 = *flagp;
    int t = blockIdx.x * 256 + threadIdx.x;
    if (t < 4096) {
        int b = t >> 9, lane = (t >> 3) & 63, j = t & 7;
        int m = b >> 1;
        int k = ((lane >> 4) << 3) + j;
        int f = ((b & 1) << 4) + (lane & 15);
        size_t idx = (size_t)k * 32 + f;
        float v = (m == 0) ? loadf(txw, idx, f32) : (m == 1) ? loadf(tdw, idx, f32)
                : (m == 2) ? loadf(trw, idx, f32) : loadf(trw, 1024 + idx, f32);
        Bfx[t] = f2bf(v);
    } else if (t < 10240) {
        int e = t - 4096;
        int b = e >> 9, lane = (e >> 3) & 63, j = e & 7;
        int m = b >> 1;
        int k = ((lane >> 4) << 3) + j;
        int f = ((b & 1) << 4) + (lane & 15);
        size_t idx = (size_t)k * 32 + f;
        float v = (m == 0) ? loadf(gyw, idx, f32) : (m == 1) ? loadf(gdw, idx, f32)
                : (m == 2) ? loadf(grw, idx, f32) : (m == 3) ? loadf(grw, 1024 + idx, f32)
                : (m == 4) ? loadf(gxw, idx, f32) : loadf(tyw, idx, f32);
        Bfy[e] = f2bf(v);
    } else if (t < 10304) {
        int f = t - 10240;
        if (f < 32) {
            bx[f] = loadf(txb, f, f32) + loadf(tdb, f, f32) + loadf(tyb, f, f32)
                  + loadf(trb, f, f32) + loadf(trb, 32 + f, f32);
        } else {
            f -= 32;
            by[f] = loadf(gyb, f, f32) + loadf(gdb, f, f32) + loadf(gxb, f, f32)
                  + loadf(grb, f, f32) + loadf(grb, 32 + f, f32);
        }
    }
}

// Pure dtype-normalizing copy: x -> xb (bf16), y -> yb (bf16).
// Gathers always read bf16 64B rows regardless of input dtype.
__global__ __launch_bounds__(256) void convert_kernel(
    const void* __restrict__ x, const void* __restrict__ y,
    u16* __restrict__ xb, u16* __restrict__ yb, const int* __restrict__ flagp)
{
    int f32 = *flagp;
    int t = blockIdx.x * 256 + threadIdx.x;
    if (t < NN * 4) {
        int r = t >> 2, q = t & 3;
        uint4 o;
        if (f32) {
            const float4* fp = (const float4*)((const float*)x + (size_t)r * 32 + q * 8);
            float4 v0 = fp[0], v1 = fp[1];
            o.x = pack2(v0.x, v0.y); o.y = pack2(v0.z, v0.w);
            o.z = pack2(v1.x, v1.y); o.w = pack2(v1.z, v1.w);
        } else {
            o = *(const uint4*)((const u16*)x + (size_t)r * 32 + q * 8);
        }
        *(uint4*)(xb + (size_t)r * 32 + q * 8) = o;
    } else if (t < MT * 4) {
        int t2 = t - NN * 4;
        int r = t2 >> 2, q = t2 & 3;
        uint4 o;
        if (f32) {
            const float4* fp = (const float4*)((const float*)y + (size_t)r * 32 + q * 8);
            float4 v0 = fp[0], v1 = fp[1];
            o.x = pack2(v0.x, v0.y); o.y = pack2(v0.z, v0.w);
            o.z = pack2(v1.x, v1.y); o.w = pack2(v1.z, v1.w);
        } else {
            o = *(const uint4*)((const u16*)y + (size_t)r * 32 + q * 8);
        }
        *(uint4*)(yb + (size_t)r * 32 + q * 8) = o;
    }
}

// Fused gather+GEMM+stats per side. Gathers RAW bf16 rows (halved working
// set: one table per side), aggregates in f32, converts the aggregate to the
// MFMA A-fragment in-register (lane m=lane&15 holds features q*8..q*8+7 with
// q=lane>>4 — exactly the 16x16x32 A layout), then chains the K-steps into
// one accumulator: self@W0 + aggT@Wr0 + aggTT@Wr1 [+ pm@Wx]. Epilogue does
// deg-scaling, bias, ReLU upper half, BN partial stats, pre-BN store.
// IS_Y runs FIRST and scatters y@theta_y into xacc (f32 atomics); the x pass
// then adds xacc directly in f32 (no extra rounding on the cross term).
template<int IS_Y>
__global__ __launch_bounds__(256, 3) void fused_side(
    const u16* __restrict__ xb, const u16* __restrict__ yb,
    float* xacc,                    // IS_Y: atomic dst; !IS_Y: read (== xpre)
    const u16* __restrict__ Bf, const float* __restrict__ bias,
    const void* __restrict__ deg,
    const int* __restrict__ tl, const int* __restrict__ ttl,
    const int* __restrict__ pm_pd, const int* __restrict__ dst,
    float* xpre, u16* __restrict__ ypre,
    float* __restrict__ stats, const int* __restrict__ flagp)
{
    __shared__ int s_t[1024];
    __shared__ int s_tt[1024];
    __shared__ float s_sum[32];
    __shared__ float s_sq[32];
    const int M = IS_Y ? NE : NN;
    int f32 = *flagp;
    int row0 = (int)blockIdx.x * 64;
    if (threadIdx.x < 32) { s_sum[threadIdx.x] = 0.f; s_sq[threadIdx.x] = 0.f; }
    int lim = (M - row0) * 16;
    for (int i = threadIdx.x; i < 1024; i += 256) {
        s_t[i]  = (i < lim) ? tl[(size_t)row0 * 16 + i]  : 0;
        s_tt[i] = (i < lim) ? ttl[(size_t)row0 * 16 + i] : 0;
    }
    __syncthreads();
    int lane = threadIdx.x & 63, wib = threadIdx.x >> 6;
    int r0 = row0 + wib * 16;
    if (r0 + 16 <= M) {   // full waves only (NN,NE are multiples of 16)
        const u16* tab = IS_Y ? yb : xb;
        int m = lane & 15, q = lane >> 4;
        int gr = r0 + m;
        const int* il  = &s_t[(wib * 16 + m) * 16];
        const int* ill = &s_tt[(wib * 16 + m) * 16];

        bf16x8 selfv = *(const bf16x8*)(tab + (size_t)gr * 32 + q * 8);
        union { u16 s[8]; bf16x8 v; } pm;
        if (IS_Y) {
            int ai = pm_pd[gr];
            pm.v = *(const bf16x8*)(xb + (size_t)ai * 32 + q * 8);
        }

        // 32 raw-row gathers, two-buffer staged: 8-16 loads in flight.
        float aT[8]  = {0.f, 0.f, 0.f, 0.f, 0.f, 0.f, 0.f, 0.f};
        float aTT[8] = {0.f, 0.f, 0.f, 0.f, 0.f, 0.f, 0.f, 0.f};
        uint4 ga[8], gb[8];
#pragma unroll
        for (int j = 0; j < 8; ++j)
            ga[j] = *(const uint4*)(tab + (size_t)il[j] * 32 + q * 8);
#pragma unroll
        for (int j = 0; j < 8; ++j)
            gb[j] = *(const uint4*)(tab + (size_t)il[8 + j] * 32 + q * 8);
#pragma unroll
        for (int j = 0; j < 8; ++j) acc8(aT, ga[j]);
#pragma unroll
        for (int j = 0; j < 8; ++j)
            ga[j] = *(const uint4*)(tab + (size_t)ill[j] * 32 + q * 8);
#pragma unroll
        for (int j = 0; j < 8; ++j) acc8(aT, gb[j]);
#pragma unroll
        for (int j = 0; j < 8; ++j)
            gb[j] = *(const uint4*)(tab + (size_t)ill[8 + j] * 32 + q * 8);
#pragma unroll
        for (int j = 0; j < 8; ++j) acc8(aTT, ga[j]);
#pragma unroll
        for (int j = 0; j < 8; ++j) acc8(aTT, gb[j]);

        union { u16 s[8]; bf16x8 v; } ft, ftt;
#pragma unroll
        for (int j = 0; j < 8; ++j) { ft.s[j] = f2bf(aT[j]); ftt.s[j] = f2bf(aTT[j]); }

        const u16* bp = Bf + lane * 8;
#define BFR(b) (*(const bf16x8*)(bp + (b) * 512))
        f32x4 z = {0.f, 0.f, 0.f, 0.f};
        f32x4 a0, a1, d0, d1, c0 = z, c1 = z;
        a0 = __builtin_amdgcn_mfma_f32_16x16x32_bf16(selfv, BFR(0), z, 0, 0, 0);
        a1 = __builtin_amdgcn_mfma_f32_16x16x32_bf16(selfv, BFR(1), z, 0, 0, 0);
        d0 = __builtin_amdgcn_mfma_f32_16x16x32_bf16(selfv, BFR(2), z, 0, 0, 0);
        d1 = __builtin_amdgcn_mfma_f32_16x16x32_bf16(selfv, BFR(3), z, 0, 0, 0);
        a0 = __builtin_amdgcn_mfma_f32_16x16x32_bf16(ft.v,  BFR(4), a0, 0, 0, 0);
        a1 = __builtin_amdgcn_mfma_f32_16x16x32_bf16(ft.v,  BFR(5), a1, 0, 0, 0);
        a0 = __builtin_amdgcn_mfma_f32_16x16x32_bf16(ftt.v, BFR(6), a0, 0, 0, 0);
        a1 = __builtin_amdgcn_mfma_f32_16x16x32_bf16(ftt.v, BFR(7), a1, 0, 0, 0);
        if (IS_Y) {
            a0 = __builtin_amdgcn_mfma_f32_16x16x32_bf16(pm.v,  BFR(8),  a0, 0, 0, 0);
            a1 = __builtin_amdgcn_mfma_f32_16x16x32_bf16(pm.v,  BFR(9),  a1, 0, 0, 0);
            c0 = __builtin_amdgcn_mfma_f32_16x16x32_bf16(selfv, BFR(10), z, 0, 0, 0);
            c1 = __builtin_amdgcn_mfma_f32_16x16x32_bf16(selfv, BFR(11), z, 0, 0, 0);
        }
#undef BFR

        // D layout: col = lane&15 (=m), row = q*4 + i
        int n = m;
        int rowb = r0 + q * 4;
        float bl_ = bias[n], bh_ = bias[16 + n];
        float s0 = 0.f, q0 = 0.f, s1 = 0.f, q1 = 0.f;
#pragma unroll
        for (int i = 0; i < 4; ++i) {
            float dgi = loadf(deg, rowb + i, f32);
            size_t ro = (size_t)(rowb + i) * 32;
            float lo = a0[i] + dgi * d0[i] + bl_;
            float hi = a1[i] + dgi * d1[i] + bh_;
            if (!IS_Y) {
                lo += xacc[ro + n];
                hi += xacc[ro + 16 + n];
            }
            hi = fmaxf(hi, 0.f);
            if (!IS_Y) {
                xpre[ro + n]      = lo;
                xpre[ro + 16 + n] = hi;
            } else {
                ypre[ro + n]      = f2bf(lo);
                ypre[ro + 16 + n] = f2bf(hi);
                int d = dst[rowb + i];
                float* p = xacc + (size_t)d * 32;
                atomicAdd(p + n,      c0[i]);
                atomicAdd(p + 16 + n, c1[i]);
            }
            s0 += lo; q0 += lo * lo;
            s1 += hi; q1 += hi * hi;
        }
        atomicAdd(&s_sum[n], s0);      atomicAdd(&s_sq[n], q0);
        atomicAdd(&s_sum[16 + n], s1); atomicAdd(&s_sq[16 + n], q1);
    }
    __syncthreads();
    if (threadIdx.x < 32) {
        float* ss = stats + (IS_Y ? 64 : 0);
        atomicAdd(&ss[threadIdx.x], s_sum[threadIdx.x]);
        atomicAdd(&ss[32 + threadIdx.x], s_sq[threadIdx.x]);
    }
}

__global__ void finalize_stats(
    const float* stats,
    const void* bnxw, const void* bnxb, const void* bnyw, const void* bnyb,
    float* scsh, const int* flagp)
{
    int f32 = *flagp;
    int f = threadIdx.x;
    if (f < 32) {
        float m = stats[f] / (float)NN;
        float var = stats[32 + f] / (float)NN - m * m;
        float inv = rsqrtf(var + 1e-5f);
        float sc = loadf(bnxw, f, f32) * inv;
        scsh[f] = sc; scsh[32 + f] = loadf(bnxb, f, f32) - m * sc;
    } else if (f < 64) {
        int g = f - 32;
        float m = stats[64 + g] / (float)NE;
        float var = stats[96 + g] / (float)NE - m * m;
        float inv = rsqrtf(var + 1e-5f);
        float sc = loadf(bnyw, g, f32) * inv;
        scsh[64 + g] = sc; scsh[96 + g] = loadf(bnyb, g, f32) - m * sc;
    }
}

__global__ __launch_bounds__(256) void apply_bn(
    const float* __restrict__ xpre, const u16* __restrict__ ypre,
    const float* __restrict__ scsh, void* __restrict__ out,
    const int* __restrict__ flagp)
{
    int f32 = *flagp;
    int tid = blockIdx.x * 256 + threadIdx.x;   // MT*8 threads, 4 elems each
    if (tid >= MT * 8) return;
    int fq = (tid & 7) * 4;
    const float* sc;
    float4 v;
    if (tid < NN * 8) {
        v = ((const float4*)xpre)[tid];
        sc = scsh;
    } else {
        size_t off = (size_t)tid * 4 - (size_t)NN * 32;
        ushort4 u = *(const ushort4*)(ypre + off);
        v.x = bf2f(u.x); v.y = bf2f(u.y); v.z = bf2f(u.z); v.w = bf2f(u.w);
        sc = scsh + 64;
    }
    float o0 = v.x * sc[fq + 0] + sc[32 + fq + 0];
    float o1 = v.y * sc[fq + 1] + sc[32 + fq + 1];
    float o2 = v.z * sc[fq + 2] + sc[32 + fq + 2];
    float o3 = v.w * sc[fq + 3] + sc[32 + fq + 3];
    if (f32) {
        float4 o; o.x = o0; o.y = o1; o.z = o2; o.w = o3;
        ((float4*)out)[tid] = o;
    } else {
        ushort4 o; o.x = f2bf(o0); o.y = f2bf(o1); o.z = f2bf(o2); o.w = f2bf(o3);
        ((ushort4*)out)[tid] = o;
    }
}

extern "C" void kernel_launch(void* const* d_in, const int* in_sizes, int n_in,
                              void* d_out, int out_size, void* d_ws, size_t ws_size,
                              hipStream_t stream)
{
    const void* x      = d_in[0];
    const void* y      = d_in[1];
    const void* deg_g  = d_in[2];
    const void* deg_lg = d_in[3];
    const int* t_g   = (const int*)d_in[4];
    const int* tt_g  = (const int*)d_in[5];
    const int* t_lg  = (const int*)d_in[6];
    const int* tt_lg = (const int*)d_in[7];
    const int* dst   = (const int*)d_in[8];
    const int* pm_pd = (const int*)d_in[9];

    char* ws = (char*)d_ws;
    int*   flag = (int*)ws;                     // 4 B
    u16* Bfx   = (u16*)(ws + 256);              // 4096 u16 = 8 KB
    u16* Bfy   = Bfx + 4096;                    // 6144 u16 = 12 KB
    float* bx  = (float*)(ws + 24576);          // 32 f32
    float* by  = bx + 32;
    float* stats = by + 32;                     // 128 f32
    float* scsh  = stats + 128;                 // 128 f32
    u16* xb    = (u16*)(ws + 65536);            // NN*32 bf16 = 6.4 MB
    u16* yb    = xb + (size_t)NN * 32;          // NE*32 bf16 = 12.8 MB
    float* xacc = (float*)(yb + (size_t)NE * 32); // NN*32 f32 = 12.8 MB (→ xpre)
    u16* ypre  = (u16*)(xacc + (size_t)NN * 32);  // NE*32 bf16 = 12.8 MB
    // total ≈ 64 KB + 44.8 MB (was 89.7 MB)

    hipMemsetAsync(stats, 0, 256 * sizeof(float), stream);
    hipMemsetAsync(xacc, 0, (size_t)NN * 32 * sizeof(float), stream);

    detect_kernel<<<1, 256, 0, stream>>>((const unsigned int*)x, flag);
    prep_kernel<<<41, 256, 0, stream>>>(
        d_in[10], d_in[12], d_in[14], d_in[16], d_in[18], d_in[20],
        d_in[22], d_in[24],
        d_in[11], d_in[13], d_in[15], d_in[17], d_in[19], d_in[21],
        d_in[23], d_in[25],
        Bfx, Bfy, bx, by, flag);
    convert_kernel<<<4688, 256, 0, stream>>>(x, y, xb, yb, flag);
    // y first: scatters y@theta_y into xacc; x then consumes xacc in f32.
    fused_side<1><<<3125, 256, 0, stream>>>(xb, yb, xacc, Bfy, by, deg_lg,
                                            t_lg, tt_lg, pm_pd, dst,
                                            (float*)0, ypre, stats, flag);
    fused_side<0><<<1563, 256, 0, stream>>>(xb, yb, xacc, Bfx, bx, deg_g,
                                            t_g, tt_g, pm_pd, dst,
                                            xacc /*xpre aliases xacc*/, (u16*)0,
                                            stats, flag);
    finalize_stats<<<1, 64, 0, stream>>>(stats, d_in[26], d_in[27], d_in[28],
                                         d_in[29], scsh, flag);
    apply_bn<<<9375, 256, 0, stream>>>(xacc, ypre, scsh, d_out, flag);
}